// Round 6
// baseline (75.531 us; speedup 1.0000x reference)
//
#include <hip/hip_runtime.h>

#define NQ     14
#define DIM    16384
#define NPAR   196
#define NCLS   10
#define NGATES 70

// ---------------- compile-time frame/gate tables ----------------
// Stored state d[h] = s_ref[A(h)], A linear over GF(2)^14.
//  - CNOT chain:  s' = s o g, g(i)=i^(i>>1)  =>  A <- g^-1 o A
//  - rotation on ref bit bp: pair h <-> h^m[bp], role = parity(h & u[bp])
//  - physical relabel sigma (bits {12,13}<->{6,7}) => m,u <- sigma(m),sigma(u)
// Layout: h = p(2b,13:12) | w(3b,11:9) | k(3b,8:6) | lane(6b,5:0)
// Per round: phase-1 = gates with m avoiding p bits {12,13}; sigma (realized as
// the coalesced inter-kernel k<->p exchange); phase-2 = the rest, now local.
struct GateInfo { int m; int u; int slot; };
struct Tables { GateInfo g[NGATES]; int mu[NQ]; int swap_at[5]; bool valid; };

constexpr unsigned swapbits(unsigned v) {   // swap bits {6,7} <-> {12,13}
    return (v & ~0x30C0u) | ((v & 0xC0u) << 6) | ((v >> 6) & 0xC0u);
}

constexpr Tables make_tables() {
    Tables T{};
    T.valid = true;
    unsigned m[NQ] = {}, u[NQ] = {};
    for (int i = 0; i < NQ; ++i) { m[i] = 1u << i; u[i] = 1u << i; }
    int gi = 0;
    for (int r = 0; r < 5; ++r) {
        bool done[NQ] = {};
        for (int q = 0; q < NQ; ++q) {            // phase 1: m avoids bits 12,13
            int bp = 13 - q;
            if ((m[bp] & 0x3000u) == 0u) {
                T.g[gi].m = (int)m[bp]; T.g[gi].u = (int)u[bp];
                T.g[gi].slot = r * 14 + q;
                done[q] = true; ++gi;
            }
        }
        T.swap_at[r] = gi;
        if (r > 0 && T.swap_at[r] <= T.swap_at[r - 1]) T.valid = false;
        for (int i = 0; i < NQ; ++i) { m[i] = swapbits(m[i]); u[i] = swapbits(u[i]); }
        for (int q = 0; q < NQ; ++q) {            // phase 2: local after sigma
            if (!done[q]) {
                int bp = 13 - q;
                if ((m[bp] & 0x3000u) != 0u) T.valid = false;
                T.g[gi].m = (int)m[bp]; T.g[gi].u = (int)u[bp];
                T.g[gi].slot = r * 14 + q;
                ++gi;
            }
        }
        if (r < 4) {                              // CNOT chain retabulation
            for (int bp = 13; bp >= 1; --bp) m[bp] ^= m[bp - 1];
            unsigned acc = 0;
            for (int bp = 13; bp >= 0; --bp) { acc ^= u[bp]; u[bp] = acc; }
        }
    }
    if (gi != NGATES) T.valid = false;
    for (int q = 0; q < NQ; ++q) T.mu[q] = (int)u[13 - q];
    return T;
}
constexpr Tables TAB = make_tables();
static_assert(TAB.valid, "gate schedule construction failed");

constexpr int seg_lo(int s) { return s == 0 ? 0 : TAB.swap_at[s - 1]; }
constexpr int seg_hi(int s) { return s < 5 ? TAB.swap_at[s] : NGATES; }
static_assert(seg_hi(0) - seg_lo(0) <= 32, "seg0");
static_assert(seg_hi(1) - seg_lo(1) <= 32, "seg1");
static_assert(seg_hi(2) - seg_lo(2) <= 32, "seg2");
static_assert(seg_hi(3) - seg_lo(3) <= 32, "seg3");
static_assert(seg_hi(4) - seg_lo(4) <= 32, "seg4");
static_assert(seg_hi(5) - seg_lo(5) <= 32, "seg5");

// ============ 256 blocks x 512 threads, A = 8 amps/thread ============
// h = p<<12 | w<<9 | k<<6 | l ;  e = blk>>2, p = blk&3, w = tid>>6, l = tid&63
// Boundary sigma ({12,13}<->{6,7}): writer amp (p,w,k,l) -> buffer slot
//   (k&3)<<12 | w<<9 | (k>>2)<<8 | p<<6 | l   (reader-linear; both sides coalesced)
template<int SEG>
__global__ void __launch_bounds__(512, 2)
qvc_seg(const float* __restrict__ x, const float2* __restrict__ gin,
        float2* __restrict__ gout, float* __restrict__ part)
{
    constexpr int LO = seg_lo(SEG);
    constexpr int HI = seg_hi(SEG);
    constexpr int NG = HI - LO;
    __shared__ __align__(16) float uc[NG][8];
    __shared__ float lds_r[8 * 512];
    __shared__ float lds_i[8 * 512];
    __shared__ float red[8][NQ];

    const int blk = blockIdx.x;
    const int e = blk >> 2, p = blk & 3;
    const int tid = threadIdx.x;
    const int w = tid >> 6, l = tid & 63;
    const int hbase = (p << 12) | (w << 9) | l;   // h minus the k bits
    const float* xb = x + e * NPAR;

    // gate coefficients: one gate per thread
    if (tid < NG) {
        const int slot = TAB.g[LO + tid].slot;
        const int layer = slot / 14, q = slot % 14;
        const int pidx = (layer < 4) ? layer * 42 + q * 3 : 168 + q * 2;
        float a1 = 0.5f * xb[pidx], a2 = 0.5f * xb[pidx + 1];
        float s1, c1, s2, c2;
        sincosf(a1, &s1, &c1);
        sincosf(a2, &s2, &c2);
        float A00r =  c2 * c1, A00i =  s2 * s1;
        float A01r = -s2 * c1, A01i = -c2 * s1;
        float A10r =  s2 * c1, A10i = -c2 * s1;
        float A11r =  c2 * c1, A11i = -s2 * s1;
        float U0, U1, U2, U3, U4, U5, U6, U7;
        if (layer < 4) {
            float a3 = 0.5f * xb[pidx + 2]; float s3, c3; sincosf(a3, &s3, &c3);
            U0 = c3 * A00r + s3 * A00i; U1 = c3 * A00i - s3 * A00r;
            U2 = c3 * A01r + s3 * A01i; U3 = c3 * A01i - s3 * A01r;
            U4 = c3 * A10r - s3 * A10i; U5 = c3 * A10i + s3 * A10r;
            U6 = c3 * A11r - s3 * A11i; U7 = c3 * A11i + s3 * A11r;
        } else {
            U0 = A00r; U1 = A00i; U2 = A01r; U3 = A01i;
            U4 = A10r; U5 = A10i; U6 = A11r; U7 = A11i;
        }
        uc[tid][0] = U0; uc[tid][1] = U1; uc[tid][2] = U2; uc[tid][3] = U3;
        uc[tid][4] = U4; uc[tid][5] = U5; uc[tid][6] = U6; uc[tid][7] = U7;
    }

    float ar[8], ai[8];
    if constexpr (SEG == 0) {
        #pragma unroll
        for (int k = 0; k < 8; ++k) { ar[k] = 0.0f; ai[k] = 0.0f; }
        if (p == 0 && tid == 0) ar[0] = 1.0f;
    } else {
        #pragma unroll
        for (int k = 0; k < 8; ++k) {
            float2 v = gin[(e << 14) | hbase | (k << 6)];
            ar[k] = v.x; ai[k] = v.y;
        }
    }
    __syncthreads();

    #pragma unroll
    for (int g = LO; g < HI; ++g) {
        const int m = TAB.g[g].m, u = TAB.g[g].u;
        const float4 c0 = *(const float4*)&uc[g - LO][0];  // {00r,00i,01r,01i}
        const float4 c1 = *(const float4*)&uc[g - LO][4];  // {10r,10i,11r,11i}
        const bool rb = (__popc(hbase & u) & 1) != 0;
        const float D0r = rb ? c1.z : c0.x, D0i = rb ? c1.w : c0.y;
        const float O0r = rb ? c1.x : c0.z, O0i = rb ? c1.y : c0.w;
        const float D1r = rb ? c0.x : c1.z, D1i = rb ? c0.y : c1.w;
        const float O1r = rb ? c0.z : c1.x, O1i = rb ? c0.w : c1.y;

        const int ml = m & 63;            // lane part
        const int mk = (m >> 6) & 7;      // reg part
        const int mw = (m >> 9) & 7;      // wave part
        float pr[8], pim[8];
        if (mw == 0 && ml == 0) {
            #pragma unroll
            for (int k = 0; k < 8; ++k) { pr[k] = ar[k ^ mk]; pim[k] = ai[k ^ mk]; }
        } else if (mw == 0) {
            #pragma unroll
            for (int k = 0; k < 8; ++k) {
                pr[k]  = __shfl_xor(ar[k ^ mk], ml, 64);
                pim[k] = __shfl_xor(ai[k ^ mk], ml, 64);
            }
        } else {
            const int tm = (mw << 6) | ml;
            __syncthreads();   // WAR: prior readers of lds done
            #pragma unroll
            for (int k = 0; k < 8; ++k) {
                lds_r[k * 512 + tid] = ar[k];
                lds_i[k * 512 + tid] = ai[k];
            }
            __syncthreads();
            #pragma unroll
            for (int k = 0; k < 8; ++k) {
                pr[k]  = lds_r[(k ^ mk) * 512 + (tid ^ tm)];
                pim[k] = lds_i[(k ^ mk) * 512 + (tid ^ tm)];
            }
        }
        const int ku = (u >> 6) & 7;
        #pragma unroll
        for (int k = 0; k < 8; ++k) {
            const int cls = __popc(k & ku) & 1;   // compile-time per k
            const float Dr = cls ? D1r : D0r, Di = cls ? D1i : D0i;
            const float Or = cls ? O1r : O0r, Oi = cls ? O1i : O0i;
            float nr = Dr * ar[k] - Di * ai[k] + Or * pr[k] - Oi * pim[k];
            float ni = Dr * ai[k] + Di * ar[k] + Or * pim[k] + Oi * pr[k];
            ar[k] = nr; ai[k] = ni;
        }
    }

    if constexpr (SEG < 5) {
        #pragma unroll
        for (int k = 0; k < 8; ++k) {
            const int idx = (e << 14) | ((k & 3) << 12) | (w << 9) |
                            ((k >> 2) << 8) | (p << 6) | l;
            gout[idx] = make_float2(ar[k], ai[k]);
        }
    } else {
        // measurement partials: E_q = sum |amp|^2 * (-1)^parity(h & mu[q])
        float eq[NQ];
        #pragma unroll
        for (int q = 0; q < NQ; ++q) eq[q] = 0.0f;
        #pragma unroll
        for (int k = 0; k < 8; ++k) {
            float p2 = ar[k] * ar[k] + ai[k] * ai[k];
            #pragma unroll
            for (int q = 0; q < NQ; ++q) {
                if (__popc(k & ((TAB.mu[q] >> 6) & 7)) & 1) eq[q] -= p2; else eq[q] += p2;
            }
        }
        #pragma unroll
        for (int q = 0; q < NQ; ++q) {
            float v = (__popc(hbase & TAB.mu[q]) & 1) ? -eq[q] : eq[q];
            #pragma unroll
            for (int off = 32; off > 0; off >>= 1) v += __shfl_down(v, off, 64);
            eq[q] = v;
        }
        if (l == 0) {
            #pragma unroll
            for (int q = 0; q < NQ; ++q) red[w][q] = eq[q];
        }
        __syncthreads();
        if (tid < NQ) {
            float s = 0.0f;
            #pragma unroll
            for (int ww = 0; ww < 8; ++ww) s += red[ww][tid];
            part[(e * 4 + p) * NQ + tid] = s;
        }
    }
}

__global__ void __launch_bounds__(64)
qvc_head(const float* __restrict__ W, const float* __restrict__ bias,
         const float* __restrict__ part, float* __restrict__ out)
{
    const int e = blockIdx.x, c = threadIdx.x;
    if (c < NCLS) {
        float acc = bias[c];
        const float* pe = part + e * 4 * NQ;
        #pragma unroll
        for (int q = 0; q < NQ; ++q) {
            float eqv = pe[q] + pe[NQ + q] + pe[2 * NQ + q] + pe[3 * NQ + q];
            acc += W[c * NQ + q] * eqv;
        }
        out[e * NCLS + c] = acc;
    }
}

extern "C" void kernel_launch(void* const* d_in, const int* in_sizes, int n_in,
                              void* d_out, int out_size, void* d_ws, size_t ws_size,
                              hipStream_t stream)
{
    const float* x    = (const float*)d_in[0];   // (64, 196)
    const float* W    = (const float*)d_in[1];   // (10, 14)
    const float* bias = (const float*)d_in[2];   // (10,)
    float*       out  = (float*)d_out;           // (64, 10)

    const size_t state_elems = (size_t)64 * DIM;          // float2 each
    float2* bufA = (float2*)d_ws;
    float2* bufB = bufA + state_elems;
    float*  part = (float*)(bufB + state_elems);
    (void)ws_size;  // observed 268 MB >> 16.03 MB needed (round-5 fill counters)

    hipLaunchKernelGGL(qvc_seg<0>, dim3(256), dim3(512), 0, stream, x, (const float2*)nullptr, bufA, (float*)nullptr);
    hipLaunchKernelGGL(qvc_seg<1>, dim3(256), dim3(512), 0, stream, x, bufA, bufB, (float*)nullptr);
    hipLaunchKernelGGL(qvc_seg<2>, dim3(256), dim3(512), 0, stream, x, bufB, bufA, (float*)nullptr);
    hipLaunchKernelGGL(qvc_seg<3>, dim3(256), dim3(512), 0, stream, x, bufA, bufB, (float*)nullptr);
    hipLaunchKernelGGL(qvc_seg<4>, dim3(256), dim3(512), 0, stream, x, bufB, bufA, (float*)nullptr);
    hipLaunchKernelGGL(qvc_seg<5>, dim3(256), dim3(512), 0, stream, x, bufA, (float2*)nullptr, part);
    hipLaunchKernelGGL(qvc_head,   dim3(64),  dim3(64),  0, stream, W, bias, part, out);
}